// Round 9
// baseline (118.717 us; speedup 1.0000x reference)
//
#include <hip/hip_runtime.h>
#include <math.h>

// Fused Actor network via single-term fp16 MFMA. Round 9: kill E1 scratch thrash.
// r7/r8: E1 held 64 f32 accs (in AGPRs, unified file) + ~64 VGPR working set = over
// the 128-reg budget at 4 waves/EU -> ~6 regs spilled per kc iter (WRITE_SIZE 150MB).
// Fix: E1 split into two 16-col passes (32 accs live); nt=0 outputs held packed fp16
// in 8 regs until nt=1's S reads finish (H1 overlays S). af loaded per-mt (not [4]).
// Block = 64 samples, 512 threads = 8 waves, LDS 66,048 B -> 2 blocks/CU.
// Weights pre-tiled in d_ws as B-fragment tiles (per-wave 1KB coalesced bursts).
// LDS XOR-swizzle: byte ^= (row&7)<<4.

typedef __attribute__((ext_vector_type(8))) _Float16 half8;
typedef __attribute__((ext_vector_type(4))) _Float16 half4;
typedef __attribute__((ext_vector_type(4))) float    f32x4;

#define MFMA16(a, b, c) __builtin_amdgcn_mfma_f32_16x16x32_f16((a), (b), (c), 0, 0, 0)
#define SWZ(row) (((row) & 7) << 4)

#define MT 64
#define T  512

// ---- LDS byte offsets (total 66,048 B) ----
// S  [0, 49152): 64 rows x 384 f16 (stride 768B); cols 376..383 zero-padded.
// G  [49152, 65536): 64x128 f16 (stride 256B). Holds G1, then G2 (A2 accs in regs).
// CF [65536, 66048): 64 x (c0h,c0l,c1h,c1l) fp16 = 8B/row.
// H1 [0, 32768): 64x256 f16 (stride 512B), overlays S (dead after E1 accumulation).
// H2 [32768, 49152): 64x128 f16 (stride 256B), overlays rest of S.
#define S_B      0
#define G_B      49152
#define CF_B     65536
#define H1_B     0
#define H2_B     32768
#define LDS_BYTES 66048

// ---- ws half-element offsets; tiled: tile(n0,kc) at ((n0*KC+kc)*512), inner [lane][8] ----
#define WS_W1 0        /* bw1: N0=8,  KC=12 -> 49152 halfs */
#define WS_W2 49152    /* bw2: N0=8,  KC=4  -> 16384 */
#define WS_E1 65536    /* ew1: N0=32, KC=12 -> 196608 */
#define WS_E2 262144   /* ew2: N0=16, KC=8  -> 65536 */
#define WS_EM 327680   /* ewm: N0=4,  KC=4  -> 8192 (2 experts x 32 rows padded) */
#define WS_HALFS 335872
#define WS_BYTES 671744

__device__ __forceinline__ half8 cvt8(const float* __restrict__ p) {
    const float4 a = *reinterpret_cast<const float4*>(p);
    const float4 b = *reinterpret_cast<const float4*>(p + 4);
    half8 r;
    r[0] = (_Float16)a.x; r[1] = (_Float16)a.y; r[2] = (_Float16)a.z; r[3] = (_Float16)a.w;
    r[4] = (_Float16)b.x; r[5] = (_Float16)b.y; r[6] = (_Float16)b.z; r[7] = (_Float16)b.w;
    return r;
}

// ================= prep kernel: fp32 weights -> fp16 B-fragment tiles in ws =================
// For W[N][K]: tile t = n0*KC + kc; half index = l*8 + j -> n = n0*16 + (l&15),
// k = kc*32 + (l>>4)*8 + j. Out-of-range (n,k) -> 0.
__global__ __launch_bounds__(256)
void prep_weights(const float* __restrict__ bw1, const float* __restrict__ bw2,
                  const float* __restrict__ ew1, const float* __restrict__ ew2,
                  const float* __restrict__ ewm, _Float16* __restrict__ wsw)
{
    const int i = blockIdx.x * 256 + threadIdx.x;
    if (i >= WS_HALFS) return;
    const float* W; int N, K, KC, j0;
    if      (i < 49152)  { W = bw1; N = 128; K = 376; KC = 12; j0 = i - WS_W1; }
    else if (i < 65536)  { W = bw2; N = 128; K = 128; KC = 4;  j0 = i - WS_W2; }
    else if (i < 262144) { W = ew1; N = 512; K = 376; KC = 12; j0 = i - WS_E1; }
    else if (i < 327680) { W = ew2; N = 256; K = 256; KC = 8;  j0 = i - WS_E2; }
    else                 { W = ewm; N = 34;  K = 128; KC = 4;  j0 = i - WS_EM; }
    const int tile = j0 >> 9;
    const int rem  = j0 & 511;
    const int l    = rem >> 3;
    const int jj   = rem & 7;
    const int n0   = tile / KC, kc = tile - n0 * KC;
    int n = n0 * 16 + (l & 15);
    const int k = kc * 32 + (l >> 4) * 8 + jj;
    float v = 0.f;
    if (W == ewm) {  // ewm logical rows: 2 experts x 32 padded rows -> src 2 x 17
        const int e = n >> 5, a = n & 31;
        if (a < 17 && k < K) v = ewm[(e * 17 + a) * K + k];
    } else {
        if (n < N && k < K) v = W[n * K + k];
    }
    wsw[i] = (_Float16)v;
}

// ================= fused actor kernel =================
template <bool USE_WS>
__global__ __launch_bounds__(512)
__attribute__((amdgpu_waves_per_eu(4, 4)))
void actor_kernel(const float* __restrict__ states,
                  const float* __restrict__ bw1, const float* __restrict__ bb1,
                  const float* __restrict__ bw2, const float* __restrict__ bb2,
                  const float* __restrict__ bwo, const float* __restrict__ bbo,
                  const float* __restrict__ ew1, const float* __restrict__ eb1,
                  const float* __restrict__ ew2, const float* __restrict__ eb2,
                  const float* __restrict__ ewm, const float* __restrict__ ebm,
                  const _Float16* __restrict__ wsw,
                  float* __restrict__ out)
{
    extern __shared__ char smc[];
    const int t    = threadIdx.x;
    const int l    = t & 63;
    const int l15  = l & 15;
    const int kgrp = l >> 4;          // 0..3
    const int kg16 = kgrp * 16;       // byte offset within a 32-col (64B) chunk
    const int wv   = __builtin_amdgcn_readfirstlane(t >> 6);
    const int base = blockIdx.x * MT;
    const int lB   = l * 8;           // half offset of this lane's frag within a ws tile

    const half8 zf = {0,0,0,0,0,0,0,0};

    // ---------- stage: states fp32 -> fp16 in LDS (swizzled) ----------
    {
        const float4* src = reinterpret_cast<const float4*>(states + (long)base * 376);
        for (int q = t; q < MT * 94; q += T) {
            const int r  = q / 94;
            const int c4 = q - r * 94;
            const float4 v = src[q];
            half4 h;
            h[0] = (_Float16)v.x; h[1] = (_Float16)v.y;
            h[2] = (_Float16)v.z; h[3] = (_Float16)v.w;
            *(half4*)(smc + S_B + ((r * 768 + c4 * 8) ^ SWZ(r))) = h;
        }
        if (t < MT) {  // zero K-pad cols 376..383 (bytes 752..768)
            *(float4*)(smc + S_B + ((t * 768 + 752) ^ SWZ(t))) = make_float4(0.f, 0.f, 0.f, 0.f);
        }
    }
    __syncthreads();

    // ---------- A1: G1 = relu(S @ bw1^T + bb1)  M=64 N=128 K=384 ----------
    {
        f32x4 acc[4] = {{0,0,0,0},{0,0,0,0},{0,0,0,0},{0,0,0,0}};
        const int col = wv * 16 + l15;
        for (int kc = 0; kc < 12; ++kc) {
            half8 bf;
            if constexpr (USE_WS) bf = *(const half8*)(wsw + WS_W1 + (wv * 12 + kc) * 512 + lB);
            else {
                const int g = kc * 4 + kgrp;
                bf = (g < 47) ? cvt8(bw1 + col * 376 + g * 8) : zf;
            }
            const int koff = kc * 64 + kg16;
            #pragma unroll
            for (int mt = 0; mt < 4; ++mt) {
                const int row = mt * 16 + l15;
                const half8 af = *(const half8*)(smc + S_B + ((row * 768 + koff) ^ SWZ(row)));
                acc[mt] = MFMA16(af, bf, acc[mt]);
            }
        }
        const float bias = bb1[col];
        #pragma unroll
        for (int mt = 0; mt < 4; ++mt) {
            #pragma unroll
            for (int j = 0; j < 4; ++j) {
                const int row = mt * 16 + kgrp * 4 + j;
                const float v = fmaxf(acc[mt][j] + bias, 0.f);
                *(_Float16*)(smc + G_B + ((row * 256 + col * 2) ^ SWZ(row))) = (_Float16)v;
            }
        }
    }
    __syncthreads();

    // ---------- A2: G2 = relu(G1 @ bw2^T + bb2)  M=64 N=128 K=128 (G reused) ----------
    {
        f32x4 acc[4] = {{0,0,0,0},{0,0,0,0},{0,0,0,0},{0,0,0,0}};
        const int col = wv * 16 + l15;
        for (int kc = 0; kc < 4; ++kc) {
            half8 bf;
            if constexpr (USE_WS) bf = *(const half8*)(wsw + WS_W2 + (wv * 4 + kc) * 512 + lB);
            else                  bf = cvt8(bw2 + col * 128 + (kc * 4 + kgrp) * 8);
            const int koff = kc * 64 + kg16;
            #pragma unroll
            for (int mt = 0; mt < 4; ++mt) {
                const int row = mt * 16 + l15;
                const half8 af = *(const half8*)(smc + G_B + ((row * 256 + koff) ^ SWZ(row)));
                acc[mt] = MFMA16(af, bf, acc[mt]);
            }
        }
        __syncthreads();   // all G1 reads complete before overwrite
        const float bias = bb2[col];
        #pragma unroll
        for (int mt = 0; mt < 4; ++mt) {
            #pragma unroll
            for (int j = 0; j < 4; ++j) {
                const int row = mt * 16 + kgrp * 4 + j;
                const float v = fmaxf(acc[mt][j] + bias, 0.f);
                *(_Float16*)(smc + G_B + ((row * 256 + col * 2) ^ SWZ(row))) = (_Float16)v;
            }
        }
    }
    __syncthreads();

    // ---------- A3: softmax coeffs -> (c0h,c0l,c1h,c1l) fp16 in CF ----------
    if (t < MT) {
        float z0 = bbo[0], z1 = bbo[1];
        for (int k8 = 0; k8 < 16; ++k8) {
            const half8 hv = *(const half8*)(smc + G_B + ((t * 256 + k8 * 16) ^ SWZ(t)));
            #pragma unroll
            for (int j = 0; j < 8; ++j) {
                const float g = (float)hv[j];
                z0 = fmaf(g, bwo[k8 * 8 + j], z0);
                z1 = fmaf(g, bwo[128 + k8 * 8 + j], z1);
            }
        }
        const float m  = fmaxf(z0, z1);
        const float e0 = __expf(z0 - m), e1 = __expf(z1 - m);
        const float inv = 1.f / (e0 + e1);
        const float c0 = e0 * inv, c1 = e1 * inv;
        half4 cc;
        cc[0] = (_Float16)c0; cc[1] = (_Float16)(c0 - (float)cc[0]);
        cc[2] = (_Float16)c1; cc[3] = (_Float16)(c1 - (float)cc[2]);
        *(half4*)(smc + CF_B + t * 8) = cc;
    }
    __syncthreads();

    // ---------- E1: H1 = relu(blend(S @ ew1[e]^T + eb1[e]))  M=64 N=256x2 K=384 ----------
    // Two 16-col passes (32 accs live each) to stay inside the 128-reg budget.
    // nt=0's outputs held packed fp16 (8 regs) until all S reads finish (H1 overlays S).
    {
        half4 hold[2][4];   // [nt][mt]
        #pragma unroll
        for (int nt = 0; nt < 2; ++nt) {
            f32x4 aA[4], aB[4];
            #pragma unroll
            for (int mt = 0; mt < 4; ++mt) { aA[mt] = {0,0,0,0}; aB[mt] = {0,0,0,0}; }
            for (int kc = 0; kc < 12; ++kc) {
                const int koff = kc * 64 + kg16;
                half8 b0, b1;
                if constexpr (USE_WS) {
                    const int n0 = wv * 2 + nt;
                    b0 = *(const half8*)(wsw + WS_E1 + (n0 * 12 + kc) * 512 + lB);
                    b1 = *(const half8*)(wsw + WS_E1 + ((16 + n0) * 12 + kc) * 512 + lB);
                } else {
                    const int g = kc * 4 + kgrp;
                    const int wr = wv * 32 + nt * 16 + l15;
                    b0 = (g < 47) ? cvt8(ew1 + wr * 376 + g * 8)         : zf;
                    b1 = (g < 47) ? cvt8(ew1 + (wr + 256) * 376 + g * 8) : zf;
                }
                #pragma unroll
                for (int mt = 0; mt < 4; ++mt) {
                    const int row = mt * 16 + l15;
                    const half8 af = *(const half8*)(smc + S_B + ((row * 768 + koff) ^ SWZ(row)));
                    aA[mt] = MFMA16(af, b0, aA[mt]);
                    aB[mt] = MFMA16(af, b1, aB[mt]);
                }
            }
            const int col = wv * 32 + nt * 16 + l15;
            const float be0 = eb1[col], be1 = eb1[256 + col];
            #pragma unroll
            for (int mt = 0; mt < 4; ++mt) {
                #pragma unroll
                for (int j = 0; j < 4; ++j) {
                    const int row = mt * 16 + kgrp * 4 + j;
                    const half4 cc = *(const half4*)(smc + CF_B + row * 8);
                    const float c0 = (float)cc[0] + (float)cc[1];
                    const float c1 = (float)cc[2] + (float)cc[3];
                    const float v = c0 * (aA[mt][j] + be0) + c1 * (aB[mt][j] + be1);
                    hold[nt][mt][j] = (_Float16)fmaxf(v, 0.f);
                }
            }
        }
        __syncthreads();   // all S reads (both passes) complete before H1 overlays S
        #pragma unroll
        for (int nt = 0; nt < 2; ++nt) {
            const int col = wv * 32 + nt * 16 + l15;
            #pragma unroll
            for (int mt = 0; mt < 4; ++mt) {
                #pragma unroll
                for (int j = 0; j < 4; ++j) {
                    const int row = mt * 16 + kgrp * 4 + j;
                    *(_Float16*)(smc + H1_B + ((row * 512 + col * 2) ^ SWZ(row))) = hold[nt][mt][j];
                }
            }
        }
    }
    __syncthreads();

    // ---------- E2: H2 = relu(blend(H1 @ ew2[e]^T + eb2[e]))  M=64 N=128x2 K=256 ----------
    {
        f32x4 cA[4], cB[4];
        #pragma unroll
        for (int mt = 0; mt < 4; ++mt) { cA[mt] = {0,0,0,0}; cB[mt] = {0,0,0,0}; }
        const int col = wv * 16 + l15;
        for (int kc = 0; kc < 8; ++kc) {
            half8 b0, b1;
            if constexpr (USE_WS) {
                b0 = *(const half8*)(wsw + WS_E2 + (wv * 8 + kc) * 512 + lB);
                b1 = *(const half8*)(wsw + WS_E2 + ((8 + wv) * 8 + kc) * 512 + lB);
            } else {
                const int g = kc * 4 + kgrp;
                b0 = cvt8(ew2 + col * 256 + g * 8);
                b1 = cvt8(ew2 + (col + 128) * 256 + g * 8);
            }
            const int koff = kc * 64 + kg16;
            #pragma unroll
            for (int mt = 0; mt < 4; ++mt) {
                const int row = mt * 16 + l15;
                const half8 af = *(const half8*)(smc + H1_B + ((row * 512 + koff) ^ SWZ(row)));
                cA[mt] = MFMA16(af, b0, cA[mt]);
                cB[mt] = MFMA16(af, b1, cB[mt]);
            }
        }
        __syncthreads();   // all H1 reads done before H2 write
        const float b0 = eb2[col], b1 = eb2[128 + col];
        #pragma unroll
        for (int mt = 0; mt < 4; ++mt) {
            #pragma unroll
            for (int j = 0; j < 4; ++j) {
                const int row = mt * 16 + kgrp * 4 + j;
                const half4 cc = *(const half4*)(smc + CF_B + row * 8);
                const float c0 = (float)cc[0] + (float)cc[1];
                const float c1 = (float)cc[2] + (float)cc[3];
                float v = c0 * (cA[mt][j] + b0) + c1 * (cB[mt][j] + b1);
                v = fmaxf(v, 0.f);
                *(_Float16*)(smc + H2_B + ((row * 256 + col * 2) ^ SWZ(row))) = (_Float16)v;
            }
        }
    }
    __syncthreads();

    // ---------- E3: mu = tanh(blend(H2 @ ewm[e]^T + ebm[e]))  M=64 N=17x2 K=128 ----------
    {
        const int colt = wv & 1;      // col tile (2x16 covers 17)
        const int mt   = wv >> 1;     // row tile 0..3
        f32x4 c0a = {0,0,0,0}, c1a = {0,0,0,0};
        const int col  = colt * 16 + l15;
        const bool vcol = (col < 17);
        const int arow = mt * 16 + l15;
        for (int kc = 0; kc < 4; ++kc) {
            const int koff = kc * 64 + kg16;
            const half8 af = *(const half8*)(smc + H2_B + ((arow * 256 + koff) ^ SWZ(arow)));
            half8 b0, b1;
            if constexpr (USE_WS) {
                b0 = *(const half8*)(wsw + WS_EM + (colt * 4 + kc) * 512 + lB);
                b1 = *(const half8*)(wsw + WS_EM + ((2 + colt) * 4 + kc) * 512 + lB);
            } else {
                const int g = kc * 4 + kgrp;
                b0 = vcol ? cvt8(ewm + col * 128 + g * 8)        : zf;
                b1 = vcol ? cvt8(ewm + (17 + col) * 128 + g * 8) : zf;
            }
            c0a = MFMA16(af, b0, c0a);
            c1a = MFMA16(af, b1, c1a);
        }
        if (vcol) {
            const float b0 = ebm[col], b1 = ebm[17 + col];
            #pragma unroll
            for (int j = 0; j < 4; ++j) {
                const int row = mt * 16 + kgrp * 4 + j;
                const half4 cc = *(const half4*)(smc + CF_B + row * 8);
                const float c0 = (float)cc[0] + (float)cc[1];
                const float c1 = (float)cc[2] + (float)cc[3];
                const float v = c0 * (c0a[j] + b0) + c1 * (c1a[j] + b1);
                out[(long)(base + row) * 17 + col] = tanhf(v);
            }
        }
    }
}

extern "C" void kernel_launch(void* const* d_in, const int* in_sizes, int n_in,
                              void* d_out, int out_size, void* d_ws, size_t ws_size,
                              hipStream_t stream) {
    (void)in_sizes; (void)n_in; (void)out_size;
    const float* states = (const float*)d_in[0];
    const float* bw1 = (const float*)d_in[1];
    const float* bb1 = (const float*)d_in[2];
    const float* bw2 = (const float*)d_in[3];
    const float* bb2 = (const float*)d_in[4];
    const float* bwo = (const float*)d_in[5];
    const float* bbo = (const float*)d_in[6];
    const float* ew1 = (const float*)d_in[7];
    const float* eb1 = (const float*)d_in[8];
    const float* ew2 = (const float*)d_in[9];
    const float* eb2 = (const float*)d_in[10];
    const float* ewm = (const float*)d_in[11];
    const float* ebm = (const float*)d_in[12];
    float* out = (float*)d_out;

    const int nblk = 65536 / MT;   // 1024

    if (d_ws != nullptr && ws_size >= (size_t)WS_BYTES) {
        _Float16* wsw = (_Float16*)d_ws;
        prep_weights<<<dim3((WS_HALFS + 255) / 256), dim3(256), 0, stream>>>(
            bw1, bw2, ew1, ew2, ewm, wsw);
        actor_kernel<true><<<dim3(nblk), dim3(T), LDS_BYTES, stream>>>(
            states, bw1, bb1, bw2, bb2, bwo, bbo,
            ew1, eb1, ew2, eb2, ewm, ebm, wsw, out);
    } else {
        actor_kernel<false><<<dim3(nblk), dim3(T), LDS_BYTES, stream>>>(
            states, bw1, bb1, bw2, bb2, bwo, bbo,
            ew1, eb1, ew2, eb2, ewm, ebm, nullptr, out);
    }
}

// Round 10
// 97.462 us; speedup vs baseline: 1.2181x; 1.2181x over previous
//
#include <hip/hip_runtime.h>
#include <math.h>

// Fused Actor network via single-term fp16 MFMA. Round 10: r8 structure, allocator unpinned.
// Evidence r7-r9: VGPR_Count stuck at 64 (=512/8: allocator targets 8 waves/EU and spills
// ~150MB scratch) regardless of waves_per_eu(4)/(4,4). r5 showed waves_per_eu(2) -> 124 regs,
// zero spill. 124 <= 128 still admits 4 waves/EU => 2 blocks/CU with 66KB LDS.
// Single change vs r8: amdgpu_waves_per_eu(2).
// Block = 64 samples, 512 threads = 8 waves, LDS 66,048 B -> 2 blocks/CU.
// Weights pre-tiled in d_ws as B-fragment tiles (per-wave 1KB coalesced bursts).
// LDS XOR-swizzle: byte ^= (row&7)<<4.

typedef __attribute__((ext_vector_type(8))) _Float16 half8;
typedef __attribute__((ext_vector_type(4))) _Float16 half4;
typedef __attribute__((ext_vector_type(4))) float    f32x4;

#define MFMA16(a, b, c) __builtin_amdgcn_mfma_f32_16x16x32_f16((a), (b), (c), 0, 0, 0)
#define SWZ(row) (((row) & 7) << 4)

#define MT 64
#define T  512

// ---- LDS byte offsets (total 66,048 B) ----
// S  [0, 49152): 64 rows x 384 f16 (stride 768B); cols 376..383 zero-padded.
// G  [49152, 65536): 64x128 f16 (stride 256B). Holds G1, then G2 (A2 accs in regs).
// CF [65536, 66048): 64 x (c0h,c0l,c1h,c1l) fp16 = 8B/row.
// H1 [0, 32768): 64x256 f16 (stride 512B), overlays S (dead after E1 accumulation).
// H2 [32768, 49152): 64x128 f16 (stride 256B), overlays rest of S.
#define S_B      0
#define G_B      49152
#define CF_B     65536
#define H1_B     0
#define H2_B     32768
#define LDS_BYTES 66048

// ---- ws half-element offsets; tiled: tile(n0,kc) at ((n0*KC+kc)*512), inner [lane][8] ----
#define WS_W1 0        /* bw1: N0=8,  KC=12 -> 49152 halfs */
#define WS_W2 49152    /* bw2: N0=8,  KC=4  -> 16384 */
#define WS_E1 65536    /* ew1: N0=32, KC=12 -> 196608 */
#define WS_E2 262144   /* ew2: N0=16, KC=8  -> 65536 */
#define WS_EM 327680   /* ewm: N0=4,  KC=4  -> 8192 (2 experts x 32 rows padded) */
#define WS_HALFS 335872
#define WS_BYTES 671744

__device__ __forceinline__ half8 cvt8(const float* __restrict__ p) {
    const float4 a = *reinterpret_cast<const float4*>(p);
    const float4 b = *reinterpret_cast<const float4*>(p + 4);
    half8 r;
    r[0] = (_Float16)a.x; r[1] = (_Float16)a.y; r[2] = (_Float16)a.z; r[3] = (_Float16)a.w;
    r[4] = (_Float16)b.x; r[5] = (_Float16)b.y; r[6] = (_Float16)b.z; r[7] = (_Float16)b.w;
    return r;
}

// ================= prep kernel: fp32 weights -> fp16 B-fragment tiles in ws =================
// For W[N][K]: tile t = n0*KC + kc; half index = l*8 + j -> n = n0*16 + (l&15),
// k = kc*32 + (l>>4)*8 + j. Out-of-range (n,k) -> 0.
__global__ __launch_bounds__(256)
void prep_weights(const float* __restrict__ bw1, const float* __restrict__ bw2,
                  const float* __restrict__ ew1, const float* __restrict__ ew2,
                  const float* __restrict__ ewm, _Float16* __restrict__ wsw)
{
    const int i = blockIdx.x * 256 + threadIdx.x;
    if (i >= WS_HALFS) return;
    const float* W; int N, K, KC, j0;
    if      (i < 49152)  { W = bw1; N = 128; K = 376; KC = 12; j0 = i - WS_W1; }
    else if (i < 65536)  { W = bw2; N = 128; K = 128; KC = 4;  j0 = i - WS_W2; }
    else if (i < 262144) { W = ew1; N = 512; K = 376; KC = 12; j0 = i - WS_E1; }
    else if (i < 327680) { W = ew2; N = 256; K = 256; KC = 8;  j0 = i - WS_E2; }
    else                 { W = ewm; N = 34;  K = 128; KC = 4;  j0 = i - WS_EM; }
    const int tile = j0 >> 9;
    const int rem  = j0 & 511;
    const int l    = rem >> 3;
    const int jj   = rem & 7;
    const int n0   = tile / KC, kc = tile - n0 * KC;
    int n = n0 * 16 + (l & 15);
    const int k = kc * 32 + (l >> 4) * 8 + jj;
    float v = 0.f;
    if (W == ewm) {  // ewm logical rows: 2 experts x 32 padded rows -> src 2 x 17
        const int e = n >> 5, a = n & 31;
        if (a < 17 && k < K) v = ewm[(e * 17 + a) * K + k];
    } else {
        if (n < N && k < K) v = W[n * K + k];
    }
    wsw[i] = (_Float16)v;
}

// ================= fused actor kernel =================
template <bool USE_WS>
__global__ __launch_bounds__(512)
__attribute__((amdgpu_waves_per_eu(2)))
void actor_kernel(const float* __restrict__ states,
                  const float* __restrict__ bw1, const float* __restrict__ bb1,
                  const float* __restrict__ bw2, const float* __restrict__ bb2,
                  const float* __restrict__ bwo, const float* __restrict__ bbo,
                  const float* __restrict__ ew1, const float* __restrict__ eb1,
                  const float* __restrict__ ew2, const float* __restrict__ eb2,
                  const float* __restrict__ ewm, const float* __restrict__ ebm,
                  const _Float16* __restrict__ wsw,
                  float* __restrict__ out)
{
    extern __shared__ char smc[];
    const int t    = threadIdx.x;
    const int l    = t & 63;
    const int l15  = l & 15;
    const int kgrp = l >> 4;          // 0..3
    const int kg16 = kgrp * 16;       // byte offset within a 32-col (64B) chunk
    const int wv   = __builtin_amdgcn_readfirstlane(t >> 6);
    const int base = blockIdx.x * MT;
    const int lB   = l * 8;           // half offset of this lane's frag within a ws tile

    const half8 zf = {0,0,0,0,0,0,0,0};

    // ---------- stage: states fp32 -> fp16 in LDS (swizzled) ----------
    {
        const float4* src = reinterpret_cast<const float4*>(states + (long)base * 376);
        for (int q = t; q < MT * 94; q += T) {
            const int r  = q / 94;
            const int c4 = q - r * 94;
            const float4 v = src[q];
            half4 h;
            h[0] = (_Float16)v.x; h[1] = (_Float16)v.y;
            h[2] = (_Float16)v.z; h[3] = (_Float16)v.w;
            *(half4*)(smc + S_B + ((r * 768 + c4 * 8) ^ SWZ(r))) = h;
        }
        if (t < MT) {  // zero K-pad cols 376..383 (bytes 752..768)
            *(float4*)(smc + S_B + ((t * 768 + 752) ^ SWZ(t))) = make_float4(0.f, 0.f, 0.f, 0.f);
        }
    }
    __syncthreads();

    // ---------- A1: G1 = relu(S @ bw1^T + bb1)  M=64 N=128 K=384 ----------
    {
        f32x4 acc[4] = {{0,0,0,0},{0,0,0,0},{0,0,0,0},{0,0,0,0}};
        const int col = wv * 16 + l15;
        for (int kc = 0; kc < 12; ++kc) {
            half8 bf;
            if constexpr (USE_WS) bf = *(const half8*)(wsw + WS_W1 + (wv * 12 + kc) * 512 + lB);
            else {
                const int g = kc * 4 + kgrp;
                bf = (g < 47) ? cvt8(bw1 + col * 376 + g * 8) : zf;
            }
            const int koff = kc * 64 + kg16;
            #pragma unroll
            for (int mt = 0; mt < 4; ++mt) {
                const int row = mt * 16 + l15;
                const half8 af = *(const half8*)(smc + S_B + ((row * 768 + koff) ^ SWZ(row)));
                acc[mt] = MFMA16(af, bf, acc[mt]);
            }
        }
        const float bias = bb1[col];
        #pragma unroll
        for (int mt = 0; mt < 4; ++mt) {
            #pragma unroll
            for (int j = 0; j < 4; ++j) {
                const int row = mt * 16 + kgrp * 4 + j;
                const float v = fmaxf(acc[mt][j] + bias, 0.f);
                *(_Float16*)(smc + G_B + ((row * 256 + col * 2) ^ SWZ(row))) = (_Float16)v;
            }
        }
    }
    __syncthreads();

    // ---------- A2: G2 = relu(G1 @ bw2^T + bb2)  M=64 N=128 K=128 (G reused) ----------
    {
        f32x4 acc[4] = {{0,0,0,0},{0,0,0,0},{0,0,0,0},{0,0,0,0}};
        const int col = wv * 16 + l15;
        for (int kc = 0; kc < 4; ++kc) {
            half8 bf;
            if constexpr (USE_WS) bf = *(const half8*)(wsw + WS_W2 + (wv * 4 + kc) * 512 + lB);
            else                  bf = cvt8(bw2 + col * 128 + (kc * 4 + kgrp) * 8);
            const int koff = kc * 64 + kg16;
            #pragma unroll
            for (int mt = 0; mt < 4; ++mt) {
                const int row = mt * 16 + l15;
                const half8 af = *(const half8*)(smc + G_B + ((row * 256 + koff) ^ SWZ(row)));
                acc[mt] = MFMA16(af, bf, acc[mt]);
            }
        }
        __syncthreads();   // all G1 reads complete before overwrite
        const float bias = bb2[col];
        #pragma unroll
        for (int mt = 0; mt < 4; ++mt) {
            #pragma unroll
            for (int j = 0; j < 4; ++j) {
                const int row = mt * 16 + kgrp * 4 + j;
                const float v = fmaxf(acc[mt][j] + bias, 0.f);
                *(_Float16*)(smc + G_B + ((row * 256 + col * 2) ^ SWZ(row))) = (_Float16)v;
            }
        }
    }
    __syncthreads();

    // ---------- A3: softmax coeffs -> (c0h,c0l,c1h,c1l) fp16 in CF ----------
    if (t < MT) {
        float z0 = bbo[0], z1 = bbo[1];
        for (int k8 = 0; k8 < 16; ++k8) {
            const half8 hv = *(const half8*)(smc + G_B + ((t * 256 + k8 * 16) ^ SWZ(t)));
            #pragma unroll
            for (int j = 0; j < 8; ++j) {
                const float g = (float)hv[j];
                z0 = fmaf(g, bwo[k8 * 8 + j], z0);
                z1 = fmaf(g, bwo[128 + k8 * 8 + j], z1);
            }
        }
        const float m  = fmaxf(z0, z1);
        const float e0 = __expf(z0 - m), e1 = __expf(z1 - m);
        const float inv = 1.f / (e0 + e1);
        const float c0 = e0 * inv, c1 = e1 * inv;
        half4 cc;
        cc[0] = (_Float16)c0; cc[1] = (_Float16)(c0 - (float)cc[0]);
        cc[2] = (_Float16)c1; cc[3] = (_Float16)(c1 - (float)cc[2]);
        *(half4*)(smc + CF_B + t * 8) = cc;
    }
    __syncthreads();

    // ---------- E1: H1 = relu(blend(S @ ew1[e]^T + eb1[e]))  M=64 N=256x2 K=384 ----------
    {
        f32x4 aA[2][4], aB[2][4];   // [nt][mt]
        #pragma unroll
        for (int nt = 0; nt < 2; ++nt)
            #pragma unroll
            for (int mt = 0; mt < 4; ++mt) { aA[nt][mt] = {0,0,0,0}; aB[nt][mt] = {0,0,0,0}; }

        for (int kc = 0; kc < 12; ++kc) {
            const int koff = kc * 64 + kg16;
            half8 af[4];
            #pragma unroll
            for (int mt = 0; mt < 4; ++mt) {
                const int row = mt * 16 + l15;
                af[mt] = *(const half8*)(smc + S_B + ((row * 768 + koff) ^ SWZ(row)));
            }
            #pragma unroll
            for (int nt = 0; nt < 2; ++nt) {
                half8 b0, b1;
                if constexpr (USE_WS) {
                    const int n0 = wv * 2 + nt;
                    b0 = *(const half8*)(wsw + WS_E1 + (n0 * 12 + kc) * 512 + lB);
                    b1 = *(const half8*)(wsw + WS_E1 + ((16 + n0) * 12 + kc) * 512 + lB);
                } else {
                    const int g = kc * 4 + kgrp;
                    const int wr = wv * 32 + nt * 16 + l15;
                    b0 = (g < 47) ? cvt8(ew1 + wr * 376 + g * 8)         : zf;
                    b1 = (g < 47) ? cvt8(ew1 + (wr + 256) * 376 + g * 8) : zf;
                }
                #pragma unroll
                for (int mt = 0; mt < 4; ++mt) {
                    aA[nt][mt] = MFMA16(af[mt], b0, aA[nt][mt]);
                    aB[nt][mt] = MFMA16(af[mt], b1, aB[nt][mt]);
                }
            }
        }
        __syncthreads();   // all S reads complete before H1 overlays S
        #pragma unroll
        for (int nt = 0; nt < 2; ++nt) {
            const int col = wv * 32 + nt * 16 + l15;
            const float b0 = eb1[col], b1 = eb1[256 + col];
            #pragma unroll
            for (int mt = 0; mt < 4; ++mt) {
                #pragma unroll
                for (int j = 0; j < 4; ++j) {
                    const int row = mt * 16 + kgrp * 4 + j;
                    const half4 cc = *(const half4*)(smc + CF_B + row * 8);
                    const float c0 = (float)cc[0] + (float)cc[1];
                    const float c1 = (float)cc[2] + (float)cc[3];
                    float v = c0 * (aA[nt][mt][j] + b0) + c1 * (aB[nt][mt][j] + b1);
                    v = fmaxf(v, 0.f);
                    *(_Float16*)(smc + H1_B + ((row * 512 + col * 2) ^ SWZ(row))) = (_Float16)v;
                }
            }
        }
    }
    __syncthreads();

    // ---------- E2: H2 = relu(blend(H1 @ ew2[e]^T + eb2[e]))  M=64 N=128x2 K=256 ----------
    {
        f32x4 cA[4], cB[4];
        #pragma unroll
        for (int mt = 0; mt < 4; ++mt) { cA[mt] = {0,0,0,0}; cB[mt] = {0,0,0,0}; }
        const int col = wv * 16 + l15;
        for (int kc = 0; kc < 8; ++kc) {
            half8 b0, b1;
            if constexpr (USE_WS) {
                b0 = *(const half8*)(wsw + WS_E2 + (wv * 8 + kc) * 512 + lB);
                b1 = *(const half8*)(wsw + WS_E2 + ((8 + wv) * 8 + kc) * 512 + lB);
            } else {
                const int g = kc * 4 + kgrp;
                b0 = cvt8(ew2 + col * 256 + g * 8);
                b1 = cvt8(ew2 + (col + 128) * 256 + g * 8);
            }
            const int koff = kc * 64 + kg16;
            #pragma unroll
            for (int mt = 0; mt < 4; ++mt) {
                const int row = mt * 16 + l15;
                const half8 af = *(const half8*)(smc + H1_B + ((row * 512 + koff) ^ SWZ(row)));
                cA[mt] = MFMA16(af, b0, cA[mt]);
                cB[mt] = MFMA16(af, b1, cB[mt]);
            }
        }
        __syncthreads();   // all H1 reads done before H2 write
        const float b0 = eb2[col], b1 = eb2[128 + col];
        #pragma unroll
        for (int mt = 0; mt < 4; ++mt) {
            #pragma unroll
            for (int j = 0; j < 4; ++j) {
                const int row = mt * 16 + kgrp * 4 + j;
                const half4 cc = *(const half4*)(smc + CF_B + row * 8);
                const float c0 = (float)cc[0] + (float)cc[1];
                const float c1 = (float)cc[2] + (float)cc[3];
                float v = c0 * (cA[mt][j] + b0) + c1 * (cB[mt][j] + b1);
                v = fmaxf(v, 0.f);
                *(_Float16*)(smc + H2_B + ((row * 256 + col * 2) ^ SWZ(row))) = (_Float16)v;
            }
        }
    }
    __syncthreads();

    // ---------- E3: mu = tanh(blend(H2 @ ewm[e]^T + ebm[e]))  M=64 N=17x2 K=128 ----------
    {
        const int colt = wv & 1;      // col tile (2x16 covers 17)
        const int mt   = wv >> 1;     // row tile 0..3
        f32x4 c0a = {0,0,0,0}, c1a = {0,0,0,0};
        const int col  = colt * 16 + l15;
        const bool vcol = (col < 17);
        const int arow = mt * 16 + l15;
        for (int kc = 0; kc < 4; ++kc) {
            const int koff = kc * 64 + kg16;
            const half8 af = *(const half8*)(smc + H2_B + ((arow * 256 + koff) ^ SWZ(arow)));
            half8 b0, b1;
            if constexpr (USE_WS) {
                b0 = *(const half8*)(wsw + WS_EM + (colt * 4 + kc) * 512 + lB);
                b1 = *(const half8*)(wsw + WS_EM + ((2 + colt) * 4 + kc) * 512 + lB);
            } else {
                const int g = kc * 4 + kgrp;
                b0 = vcol ? cvt8(ewm + col * 128 + g * 8)        : zf;
                b1 = vcol ? cvt8(ewm + (17 + col) * 128 + g * 8) : zf;
            }
            c0a = MFMA16(af, b0, c0a);
            c1a = MFMA16(af, b1, c1a);
        }
        if (vcol) {
            const float b0 = ebm[col], b1 = ebm[17 + col];
            #pragma unroll
            for (int j = 0; j < 4; ++j) {
                const int row = mt * 16 + kgrp * 4 + j;
                const half4 cc = *(const half4*)(smc + CF_B + row * 8);
                const float c0 = (float)cc[0] + (float)cc[1];
                const float c1 = (float)cc[2] + (float)cc[3];
                const float v = c0 * (c0a[j] + b0) + c1 * (c1a[j] + b1);
                out[(long)(base + row) * 17 + col] = tanhf(v);
            }
        }
    }
}

extern "C" void kernel_launch(void* const* d_in, const int* in_sizes, int n_in,
                              void* d_out, int out_size, void* d_ws, size_t ws_size,
                              hipStream_t stream) {
    (void)in_sizes; (void)n_in; (void)out_size;
    const float* states = (const float*)d_in[0];
    const float* bw1 = (const float*)d_in[1];
    const float* bb1 = (const float*)d_in[2];
    const float* bw2 = (const float*)d_in[3];
    const float* bb2 = (const float*)d_in[4];
    const float* bwo = (const float*)d_in[5];
    const float* bbo = (const float*)d_in[6];
    const float* ew1 = (const float*)d_in[7];
    const float* eb1 = (const float*)d_in[8];
    const float* ew2 = (const float*)d_in[9];
    const float* eb2 = (const float*)d_in[10];
    const float* ewm = (const float*)d_in[11];
    const float* ebm = (const float*)d_in[12];
    float* out = (float*)d_out;

    const int nblk = 65536 / MT;   // 1024

    if (d_ws != nullptr && ws_size >= (size_t)WS_BYTES) {
        _Float16* wsw = (_Float16*)d_ws;
        prep_weights<<<dim3((WS_HALFS + 255) / 256), dim3(256), 0, stream>>>(
            bw1, bw2, ew1, ew2, ewm, wsw);
        actor_kernel<true><<<dim3(nblk), dim3(T), LDS_BYTES, stream>>>(
            states, bw1, bb1, bw2, bb2, bwo, bbo,
            ew1, eb1, ew2, eb2, ewm, ebm, wsw, out);
    } else {
        actor_kernel<false><<<dim3(nblk), dim3(T), LDS_BYTES, stream>>>(
            states, bw1, bb1, bw2, bb2, bwo, bbo,
            ew1, eb1, ew2, eb2, ewm, ebm, nullptr, out);
    }
}